// Round 1
// baseline (3409.530 us; speedup 1.0000x reference)
//
#include <hip/hip_runtime.h>

// SDPA fp32 baseline: B=2 H=16 L=2048 D=64.
// One block = 16 query rows of one (b,h). Full score rows live in LDS (fp32),
// softmax in place, normalized P written to global attention, then P@V with
// V tiles staged through the same LDS buffer as K.

#define L_SEQ 2048
#define D_HEAD 64
#define N_BH 32          // B*H
#define TQ 16            // queries per block
#define TK 64            // K/V rows per LDS tile
#define SP 2056          // padded S row stride (floats): qi banks 8 apart
#define KP 68            // padded K/V tile row stride (floats): 2-way max
#define NT 256

__global__ __launch_bounds__(NT)
void sdpa_fp32_kernel(const float* __restrict__ qg,
                      const float* __restrict__ kg,
                      const float* __restrict__ vg,
                      float* __restrict__ ctx,
                      float* __restrict__ attn)
{
    extern __shared__ float lds[];
    float* S   = lds;                 // [TQ][SP]  scores -> exp values
    float* KT  = lds + TQ * SP;       // [TK][KP]  K tile, then V tiles
    float* INV = KT + TK * KP;        // [TQ]      1/rowsum

    const int t  = threadIdx.x;
    const int bh = blockIdx.y;
    const int q0 = blockIdx.x * TQ;

    const float* qb = qg + ((size_t)bh * L_SEQ + q0) * D_HEAD;
    const float* kb = kg + (size_t)bh * L_SEQ * D_HEAD;
    const float* vb = vg + (size_t)bh * L_SEQ * D_HEAD;
    float* ab = attn + ((size_t)bh * L_SEQ + q0) * (size_t)L_SEQ;
    float* cb = ctx  + ((size_t)bh * L_SEQ + q0) * D_HEAD;

    const int qi = t >> 4;   // 0..15: this thread's query row (fixed)
    const int jg = t & 15;   // 0..15: j-group / d-group lane

    // q row in registers (16 threads per row read the same 64 floats; L1-served)
    float4 qr[16];
    {
        const float4* qrow = (const float4*)(qb + qi * D_HEAD);
        #pragma unroll
        for (int i = 0; i < 16; ++i) qr[i] = qrow[i];
    }

    const float scale = 0.125f;  // 1/sqrt(64)

    // ---- Phase 1: S = scale * Q K^T, tile by tile over keys ----
    for (int kt = 0; kt < L_SEQ / TK; ++kt) {
        __syncthreads();  // previous tile's KT reads complete
        #pragma unroll
        for (int ii = 0; ii < 4; ++ii) {
            int idx = ii * NT + t;
            int r = idx >> 4, c4 = idx & 15;
            float4 val = ((const float4*)(kb + (size_t)(kt * TK + r) * D_HEAD))[c4];
            *(float4*)(KT + r * KP + c4 * 4) = val;
        }
        __syncthreads();
        float s0 = 0.f, s1 = 0.f, s2 = 0.f, s3 = 0.f;
        #pragma unroll
        for (int i4 = 0; i4 < 16; ++i4) {
            float4 qv = qr[i4];
            float4 k0 = *(const float4*)(KT + (jg      ) * KP + i4 * 4);
            float4 k1 = *(const float4*)(KT + (jg + 16) * KP + i4 * 4);
            float4 k2 = *(const float4*)(KT + (jg + 32) * KP + i4 * 4);
            float4 k3 = *(const float4*)(KT + (jg + 48) * KP + i4 * 4);
            s0 += qv.x*k0.x + qv.y*k0.y + qv.z*k0.z + qv.w*k0.w;
            s1 += qv.x*k1.x + qv.y*k1.y + qv.z*k1.z + qv.w*k1.w;
            s2 += qv.x*k2.x + qv.y*k2.y + qv.z*k2.z + qv.w*k2.w;
            s3 += qv.x*k3.x + qv.y*k3.y + qv.z*k3.z + qv.w*k3.w;
        }
        float* srow = S + qi * SP + kt * TK;
        srow[jg     ] = s0 * scale;
        srow[jg + 16] = s1 * scale;
        srow[jg + 32] = s2 * scale;
        srow[jg + 48] = s3 * scale;
    }
    __syncthreads();

    // ---- Phase 2: softmax per row (16 lanes of one wave per row) ----
    {
        float m = -3.0e38f;
        for (int c = jg; c < L_SEQ; c += 16) m = fmaxf(m, S[qi * SP + c]);
        #pragma unroll
        for (int off = 8; off; off >>= 1) m = fmaxf(m, __shfl_xor(m, off));
        float sum = 0.f;
        for (int c = jg; c < L_SEQ; c += 16) {
            float e = __expf(S[qi * SP + c] - m);
            S[qi * SP + c] = e;
            sum += e;
        }
        #pragma unroll
        for (int off = 8; off; off >>= 1) sum += __shfl_xor(sum, off);
        if (jg == 0) INV[qi] = 1.0f / sum;
    }
    __syncthreads();

    // ---- Phase 3a: write normalized attention (coalesced 1 KiB/wave) ----
    #pragma unroll 4
    for (int c = 0; c < 32; ++c) {
        int idx = c * NT + t;       // 0..8191 float4s over the 16x2048 tile
        int r = idx >> 9;           // row (uniform per iteration)
        int c4 = idx & 511;
        float4 e4 = *(const float4*)(S + r * SP + c4 * 4);
        float iv = INV[r];
        e4.x *= iv; e4.y *= iv; e4.z *= iv; e4.w *= iv;
        ((float4*)(ab + (size_t)r * L_SEQ))[c4] = e4;
    }

    // ---- Phase 3b: context = (unnormalized P) @ V, scale by INV at end ----
    float4 acc = make_float4(0.f, 0.f, 0.f, 0.f);
    const int dg = jg;   // d-group: columns dg*4 .. dg*4+3
    for (int vt = 0; vt < L_SEQ / TK; ++vt) {
        __syncthreads();
        #pragma unroll
        for (int ii = 0; ii < 4; ++ii) {
            int idx = ii * NT + t;
            int r = idx >> 4, c4 = idx & 15;
            float4 val = ((const float4*)(vb + (size_t)(vt * TK + r) * D_HEAD))[c4];
            *(float4*)(KT + r * KP + c4 * 4) = val;
        }
        __syncthreads();
        const float* prow = S + qi * SP + vt * TK;
        #pragma unroll
        for (int j4 = 0; j4 < 16; ++j4) {
            float4 p4 = *(const float4*)(prow + j4 * 4);
            float4 a0 = *(const float4*)(KT + (j4 * 4 + 0) * KP + dg * 4);
            float4 a1 = *(const float4*)(KT + (j4 * 4 + 1) * KP + dg * 4);
            float4 a2 = *(const float4*)(KT + (j4 * 4 + 2) * KP + dg * 4);
            float4 a3 = *(const float4*)(KT + (j4 * 4 + 3) * KP + dg * 4);
            acc.x += p4.x*a0.x + p4.y*a1.x + p4.z*a2.x + p4.w*a3.x;
            acc.y += p4.x*a0.y + p4.y*a1.y + p4.z*a2.y + p4.w*a3.y;
            acc.z += p4.x*a0.z + p4.y*a1.z + p4.z*a2.z + p4.w*a3.z;
            acc.w += p4.x*a0.w + p4.y*a1.w + p4.z*a2.w + p4.w*a3.w;
        }
    }
    {
        float iv = INV[qi];
        acc.x *= iv; acc.y *= iv; acc.z *= iv; acc.w *= iv;
        ((float4*)(cb + qi * D_HEAD))[dg] = acc;
    }
}

extern "C" void kernel_launch(void* const* d_in, const int* in_sizes, int n_in,
                              void* d_out, int out_size, void* d_ws, size_t ws_size,
                              hipStream_t stream) {
    const float* q = (const float*)d_in[0];
    const float* k = (const float*)d_in[1];
    const float* v = (const float*)d_in[2];
    float* ctx  = (float*)d_out;
    float* attn = ctx + (size_t)N_BH * L_SEQ * D_HEAD;  // context first, then attention

    dim3 grid(L_SEQ / TQ, N_BH);   // 128 x 32 = 4096 blocks
    size_t smem = (size_t)(TQ * SP + TK * KP + TQ) * sizeof(float);  // 149056 B
    hipLaunchKernelGGL(sdpa_fp32_kernel, grid, dim3(NT), smem, stream,
                       q, k, v, ctx, attn);
}